// Round 1
// baseline (874.530 us; speedup 1.0000x reference)
//
#include <hip/hip_runtime.h>
#include <hip/hip_bf16.h>
#include <stdint.h>

// BinaryTreeLSTM on MI355X (gfx950).
// B=256, DEPTH=10, N=1023 nodes (heap order), IN=H=128, gdim=384, C=5.
// Per level d (9..0): for n=2^d nodes, gates = [x | h_l | h_r] @ W^T + b for
// 5 gates (i,fl,fr,o,u), then c = i*u + fl*cl + fr*cr, h = o*tanh(c).
// Leaf level: children are zero => K collapses to 128 and cl=cr=0.
//
// Design round 0:
//  - bf16 MFMA 16x16x32, fp32 accum. h stored bf16 (GEMM input anyway),
//    c stored fp32 (elementwise only). Ping-pong buffers in d_ws (~201 MB).
//  - One fused kernel per level: GEMM tile 64m x 32j x 5 gates per block
//    (256 thr / 4 waves; wave = 32m x 16j x 5g = 10 MFMA accums).
//  - LDS single-buffered, BK=64, pitch 72 bf16 (2-way bank alias = free).
//  - Fragment layouts per learn_hip m89/m74 (A/B: row=lane&15,k=quad*8+i;
//    D: n=lane&15, m=quad*4+reg).

#define BATCH 256
#define TDEPTH 10
#define NTOT 1023
#define HDIM 128
#define NCLS 5
#define GDIM 384

typedef __bf16 bf16x8 __attribute__((ext_vector_type(8)));
typedef float f32x4 __attribute__((ext_vector_type(4)));

struct alignas(8) bf4_t { __bf16 v[4]; };

__device__ __forceinline__ float sigmoid_f(float v) { return 1.f / (1.f + __expf(-v)); }
// tanh via exp(2x) form: saturates correctly at +/-1 for large |x| (no inf/inf NaN).
__device__ __forceinline__ float tanh_f(float v) { return 1.f - 2.f / (1.f + __expf(2.f * v)); }

constexpr int PA = 72;  // LDS pitch (bf16) for A tile: 64 + 8 pad
constexpr int PB = 72;  // LDS pitch (bf16) for B tile

__device__ __forceinline__ bf4_t cvt4(float4 v) {
  bf4_t o;
  o.v[0] = (__bf16)v.x; o.v[1] = (__bf16)v.y; o.v[2] = (__bf16)v.z; o.v[3] = (__bf16)v.w;
  return o;
}

__global__ __launch_bounds__(256) void level_kernel(
    const float* __restrict__ x,
    const float* __restrict__ W0, const float* __restrict__ W1,
    const float* __restrict__ W2, const float* __restrict__ W3,
    const float* __restrict__ W4,
    const float* __restrict__ bv0, const float* __restrict__ bv1,
    const float* __restrict__ bv2, const float* __restrict__ bv3,
    const float* __restrict__ bv4,
    const __bf16* __restrict__ h_prev, const float* __restrict__ c_prev,
    __bf16* __restrict__ h_out, float* __restrict__ c_out,
    int n, int log2n, int leaf)
{
  __shared__ __bf16 As[64 * PA];    // 64 m-rows x 64 k (padded)
  __shared__ __bf16 Bs[160 * PB];   // 5 gates x 32 j x 64 k (padded)

  const int tid  = threadIdx.x;
  const int lane = tid & 63;
  const int wave = tid >> 6;
  const int wm = wave >> 1;         // wave m-half (0..1)
  const int wj = wave & 1;          // wave j-half (0..1)
  const int l15 = lane & 15;
  const int quad = lane >> 4;
  const int m0 = blockIdx.x * 64;
  const int j0 = blockIdx.y * 32;
  const int start = n - 1;

  f32x4 acc[2][5];
#pragma unroll
  for (int mt = 0; mt < 2; ++mt)
#pragma unroll
    for (int g = 0; g < 5; ++g)
      acc[mt][g] = (f32x4){0.f, 0.f, 0.f, 0.f};

  const int nk = leaf ? 2 : 6;      // K-tiles of 64; leaf uses only the x part
  for (int kt = 0; kt < nk; ++kt) {
    const int k0 = kt * 64;
    __syncthreads();
    // ---- stage A (comb tile): 64 rows x 64 k = 1024 float4-groups, 4/thread
#pragma unroll
    for (int it = 0; it < 4; ++it) {
      int ee = tid + it * 256;
      int row = ee >> 4, kv = ee & 15;
      int m = m0 + row;
      int b = m >> log2n;
      int idx = m & (n - 1);
      int kg = k0 + kv * 4;
      __bf16* dst = &As[row * PA + kv * 4];
      if (kg < 128) {
        // x region: fp32 -> bf16
        const float4 vv = *(const float4*)(x + ((size_t)(b * NTOT + start + idx)) * 128 + kg);
        *(bf4_t*)dst = cvt4(vv);
      } else {
        // h region: kg in [128,256) -> left child, [256,384) -> right child
        int child = 2 * idx + ((kg >> 7) - 1);
        int kk = kg & 127;
        *(bf4_t*)dst = *(const bf4_t*)(h_prev + ((size_t)(b * 2 * n + child)) * 128 + kk);
      }
    }
    // ---- stage B (weights): 5 gates x 32 rows x 16 float4, 10/thread
#pragma unroll
    for (int g = 0; g < 5; ++g) {
      const float* __restrict__ Wg = (g == 0) ? W0 : (g == 1) ? W1 : (g == 2) ? W2 : (g == 3) ? W3 : W4;
#pragma unroll
      for (int s = 0; s < 2; ++s) {
        int ee = tid + s * 256;
        int kv = ee & 15, jr = ee >> 4;
        const float4 vv = *(const float4*)(Wg + (size_t)(j0 + jr) * GDIM + k0 + kv * 4);
        *(bf4_t*)&Bs[(g * 32 + jr) * PB + kv * 4] = cvt4(vv);
      }
    }
    __syncthreads();
    // ---- MFMA: 2 k-steps of 32 per K-tile
#pragma unroll
    for (int ks = 0; ks < 2; ++ks) {
      bf16x8 a0 = *(const bf16x8*)&As[(wm * 32 + l15) * PA + ks * 32 + quad * 8];
      bf16x8 a1 = *(const bf16x8*)&As[(wm * 32 + 16 + l15) * PA + ks * 32 + quad * 8];
#pragma unroll
      for (int g = 0; g < 5; ++g) {
        bf16x8 bb = *(const bf16x8*)&Bs[(g * 32 + wj * 16 + l15) * PB + ks * 32 + quad * 8];
        acc[0][g] = __builtin_amdgcn_mfma_f32_16x16x32_bf16(a0, bb, acc[0][g], 0, 0, 0);
        acc[1][g] = __builtin_amdgcn_mfma_f32_16x16x32_bf16(a1, bb, acc[1][g], 0, 0, 0);
      }
    }
  }

  // ---- epilogue: thread holds all 5 gates for its (m,j) elements.
  // D layout: j (n-dim) = lane&15, m (within 16-tile) = quad*4 + reg.
  const int j = j0 + wj * 16 + l15;
  const float bi  = bv0[j], bfl = bv1[j], bfr = bv2[j], bo = bv3[j], bu = bv4[j];
#pragma unroll
  for (int mt = 0; mt < 2; ++mt) {
#pragma unroll
    for (int r = 0; r < 4; ++r) {
      int ml = wm * 32 + mt * 16 + quad * 4 + r;
      int m = m0 + ml;
      int b = m >> log2n;
      int idx = m & (n - 1);
      float gi = sigmoid_f(acc[mt][0][r] + bi);
      float gl = sigmoid_f(acc[mt][1][r] + bfl);
      float gr = sigmoid_f(acc[mt][2][r] + bfr);
      float go = sigmoid_f(acc[mt][3][r] + bo);
      float gu = tanh_f(acc[mt][4][r] + bu);
      float cv = gi * gu;
      if (!leaf) {
        size_t cb = ((size_t)(b * 2 * n + 2 * idx)) * 128 + j;
        cv += gl * c_prev[cb] + gr * c_prev[cb + 128];
      }
      float hv = go * tanh_f(cv);
      size_t ob = ((size_t)(b * n + idx)) * 128 + j;
      c_out[ob] = cv;
      h_out[ob] = (__bf16)hv;
    }
  }
}

__global__ __launch_bounds__(256) void cls_kernel(
    const __bf16* __restrict__ hroot, const float* __restrict__ Wc,
    const float* __restrict__ bc, float* __restrict__ out)
{
  int t = blockIdx.x * blockDim.x + threadIdx.x;
  if (t >= BATCH * NCLS) return;
  int b = t / NCLS, ci = t % NCLS;
  float s = bc[ci];
#pragma unroll 4
  for (int jj = 0; jj < HDIM; ++jj)
    s += (float)hroot[b * HDIM + jj] * Wc[ci * HDIM + jj];
  out[t] = s;
}

extern "C" void kernel_launch(void* const* d_in, const int* in_sizes, int n_in,
                              void* d_out, int out_size, void* d_ws, size_t ws_size,
                              hipStream_t stream) {
  const float* x  = (const float*)d_in[0];
  const float* W[5]  = {(const float*)d_in[1], (const float*)d_in[3], (const float*)d_in[5],
                        (const float*)d_in[7], (const float*)d_in[9]};
  const float* bv[5] = {(const float*)d_in[2], (const float*)d_in[4], (const float*)d_in[6],
                        (const float*)d_in[8], (const float*)d_in[10]};
  const float* Wcls = (const float*)d_in[11];
  const float* bcls = (const float*)d_in[12];

  // Workspace: ping-pong h (bf16) and c (fp32), each sized B x 512 x H.
  const size_t HC = (size_t)BATCH * 512 * HDIM;   // 16,777,216 elements
  uint8_t* ws = (uint8_t*)d_ws;
  __bf16* hbuf[2] = {(__bf16*)ws, (__bf16*)ws + HC};
  float*  cbuf[2] = {(float*)(ws + 2 * HC * sizeof(__bf16)),
                     (float*)(ws + 2 * HC * sizeof(__bf16)) + HC};

  for (int d = TDEPTH - 1; d >= 0; --d) {
    int n = 1 << d;
    int wi = (TDEPTH - 1 - d) & 1;  // write buffer index
    int ri = wi ^ 1;                // read buffer index (children)
    int leaf = (d == TDEPTH - 1) ? 1 : 0;
    dim3 grid(4 * n, 4);            // M/64 x (128/32)
    level_kernel<<<grid, 256, 0, stream>>>(
        x, W[0], W[1], W[2], W[3], W[4],
        bv[0], bv[1], bv[2], bv[3], bv[4],
        hbuf[ri], cbuf[ri],     // unused when leaf=1 (never dereferenced)
        hbuf[wi], cbuf[wi], n, d, leaf);
  }
  // root h is in write-buffer of d=0: wi = 9 & 1 = 1
  cls_kernel<<<(BATCH * NCLS + 255) / 256, 256, 0, stream>>>(hbuf[1], Wcls, bcls, (float*)d_out);
}

// Round 2
// 572.328 us; speedup vs baseline: 1.5280x; 1.5280x over previous
//
#include <hip/hip_runtime.h>
#include <hip/hip_bf16.h>
#include <stdint.h>

// BinaryTreeLSTM on MI355X (gfx950) — round 2.
// Structure: per level, fused GEMM (comb[M x 384] @ W^T[640 x 384]) + LSTM cell.
//  - 32x32x16 bf16 MFMA (4x MACs per LDS byte vs 16x16x32).
//  - Weights pre-packed to bf16 in fragment order (PW), staged with
//    global_load_lds width=16 (wave-uniform LDS base + lane*16 layout).
//  - Block tile 128m x (64j x 5 gates), 256 thr / 4 waves (2wm x 2wj),
//    wave = 64m x 32j x 5g = 10 accums of f32x16 (160 VGPR).
//  - BK=32 double-buffered LDS: (A 8KB + B 20KB) x 2 = 56KB -> 2 blocks/CU.
//  - x region (k<128) read fp32 + converted in-register during staging;
//    h-children region staged via per-lane-address global_load_lds (bf16).
//  - c kept fp32 (precision margin), h stored bf16.

#define BATCH 256
#define TDEPTH 10
#define NTOT 1023
#define HDIM 128
#define NCLS 5
#define GDIM 384
#define NKS 24   // k-steps of 16 across GDIM
#define NJT 4    // j-tiles of 32 across HDIM

typedef __bf16 bf16x8 __attribute__((ext_vector_type(8)));
typedef float f32x16 __attribute__((ext_vector_type(16)));

__device__ __forceinline__ float sigmoid_f(float v) { return 1.f / (1.f + __expf(-v)); }
__device__ __forceinline__ float tanh_f(float v) { return 1.f - 2.f / (1.f + __expf(2.f * v)); }

__device__ __forceinline__ void load_lds16(const void* g, void* l) {
  __builtin_amdgcn_global_load_lds((const __attribute__((address_space(1))) unsigned int*)g,
                                   (__attribute__((address_space(3))) unsigned int*)l, 16, 0, 0);
}

// Pack W[g] (128 x 384 fp32) into bf16 fragment order:
// PW[((g*4 + jt)*24 + ks)*64 + lane][8], elem (lane,i) = W[jt*32+(lane&31)][ks*16+(lane>>5)*8+i]
__global__ __launch_bounds__(256) void pack_w(
    const float* __restrict__ W0, const float* __restrict__ W1, const float* __restrict__ W2,
    const float* __restrict__ W3, const float* __restrict__ W4, __bf16* __restrict__ PW)
{
  int t = blockIdx.x * 256 + threadIdx.x;   // 30720 total
  int lane = t & 63;
  int rest = t >> 6;         // (g*4+jt)*24 + ks, 0..479
  int ks = rest % NKS;
  int r2 = rest / NKS;       // g*4 + jt
  int jt = r2 & 3;
  int g = r2 >> 2;
  const float* W = (g == 0) ? W0 : (g == 1) ? W1 : (g == 2) ? W2 : (g == 3) ? W3 : W4;
  const float* s = W + (size_t)(jt * 32 + (lane & 31)) * GDIM + ks * 16 + (lane >> 5) * 8;
  float4 v0 = *(const float4*)s;
  float4 v1 = *(const float4*)(s + 4);
  bf16x8 w;
  w[0] = (__bf16)v0.x; w[1] = (__bf16)v0.y; w[2] = (__bf16)v0.z; w[3] = (__bf16)v0.w;
  w[4] = (__bf16)v1.x; w[5] = (__bf16)v1.y; w[6] = (__bf16)v1.z; w[7] = (__bf16)v1.w;
  *(bf16x8*)(PW + (size_t)t * 8) = w;
}

__global__ __launch_bounds__(256, 2) void level_kernel(
    const float* __restrict__ x, const __bf16* __restrict__ PW,
    const float* __restrict__ bv0, const float* __restrict__ bv1,
    const float* __restrict__ bv2, const float* __restrict__ bv3,
    const float* __restrict__ bv4,
    const __bf16* __restrict__ h_prev, const float* __restrict__ c_prev,
    __bf16* __restrict__ h_out, float* __restrict__ c_out,
    int n, int log2n, int leaf)
{
  __shared__ unsigned char lds[2 * 28672];  // per buf: A 8KB | B 20KB

  const int tid = threadIdx.x;
  const int lane = tid & 63;
  const int wave = tid >> 6;
  const int wm = wave >> 1, wj = wave & 1;
  const int l31 = lane & 31;
  const int half8 = (lane >> 5) * 8;
  const int m0 = blockIdx.x * 128;
  const int jt0 = blockIdx.y * 2;
  const int nk = leaf ? 4 : 12;

  // Staging row for this lane (wave stages m-subtile == wave index)
  const int am = m0 + wave * 32 + l31;
  const int ab = am >> log2n;
  const int aidx = am & (n - 1);
  const size_t xrow = ((size_t)ab * NTOT + (n - 1) + aidx) * HDIM;
  const size_t hrowL = ((size_t)ab * 2 * n + 2 * aidx) * HDIM;  // left child base

  auto stage = [&](int kt, int buf) {
    unsigned char* Ab = lds + buf * 28672;
    unsigned char* Bb = Ab + 8192;
    // B: 20 chunks of 1KB, 5 per wave. chunk c = ((g*2+jj)*2+kk)
#pragma unroll
    for (int q = 0; q < 5; ++q) {
      int c = wave * 5 + q;
      int g = c >> 2, jj = (c >> 1) & 1, kk = c & 1;
      const __bf16* s = PW + (((size_t)(g * NJT + jt0 + jj) * NKS + (kt * 2 + kk)) * 64 + lane) * 8;
      load_lds16(s, Bb + c * 1024);
    }
    // A: wave stages rows [m0+32*wave, +32), both k-halves of the BK=32 tile
    if (kt < 4) {
      // x region (fp32 -> bf16 in-register)
#pragma unroll
      for (int kk = 0; kk < 2; ++kk) {
        int k = kt * 32 + kk * 16 + half8;
        const float* s = x + xrow + k;
        float4 v0 = *(const float4*)s;
        float4 v1 = *(const float4*)(s + 4);
        bf16x8 w;
        w[0] = (__bf16)v0.x; w[1] = (__bf16)v0.y; w[2] = (__bf16)v0.z; w[3] = (__bf16)v0.w;
        w[4] = (__bf16)v1.x; w[5] = (__bf16)v1.y; w[6] = (__bf16)v1.z; w[7] = (__bf16)v1.w;
        *(bf16x8*)(Ab + (wave * 2 + kk) * 1024 + lane * 16) = w;
      }
    } else {
      // h region: k in [128,256) left child, [256,384) right child (bf16 direct)
#pragma unroll
      for (int kk = 0; kk < 2; ++kk) {
        int k = kt * 32 + kk * 16 + half8;
        const __bf16* s = h_prev + hrowL + (k >= 256 ? HDIM : 0) + (k & 127);
        load_lds16(s, Ab + (wave * 2 + kk) * 1024);
      }
    }
  };

  f32x16 acc[2][5];
#pragma unroll
  for (int mt = 0; mt < 2; ++mt)
#pragma unroll
    for (int g = 0; g < 5; ++g)
#pragma unroll
      for (int r = 0; r < 16; ++r) acc[mt][g][r] = 0.f;

  stage(0, 0);
  for (int kt = 0; kt < nk; ++kt) {
    __syncthreads();                       // buf[kt&1] ready; buf[kt+1&1] free
    if (kt + 1 < nk) stage(kt + 1, (kt + 1) & 1);
    const unsigned char* Ab = lds + (kt & 1) * 28672;
    const unsigned char* Bb = Ab + 8192;
#pragma unroll
    for (int kk = 0; kk < 2; ++kk) {
      bf16x8 a0 = *(const bf16x8*)(Ab + ((wm * 2 + 0) * 2 + kk) * 1024 + lane * 16);
      bf16x8 a1 = *(const bf16x8*)(Ab + ((wm * 2 + 1) * 2 + kk) * 1024 + lane * 16);
#pragma unroll
      for (int g = 0; g < 5; ++g) {
        bf16x8 bb = *(const bf16x8*)(Bb + ((g * 2 + wj) * 2 + kk) * 1024 + lane * 16);
        acc[0][g] = __builtin_amdgcn_mfma_f32_32x32x16_bf16(a0, bb, acc[0][g], 0, 0, 0);
        acc[1][g] = __builtin_amdgcn_mfma_f32_32x32x16_bf16(a1, bb, acc[1][g], 0, 0, 0);
      }
    }
  }

  // Epilogue. D layout (32x32): col(j) = lane&31, row(m) = (r&3) + 8*(r>>2) + 4*(lane>>5)
  const int j = jt0 * 32 + wj * 32 + l31;
  const float b0 = bv0[j], b1 = bv1[j], b2 = bv2[j], b3 = bv3[j], b4 = bv4[j];
  const int rh = (lane >> 5) * 4;
#pragma unroll
  for (int mt = 0; mt < 2; ++mt) {
    const int mb = m0 + (wm * 2 + mt) * 32 + rh;
#pragma unroll
    for (int r = 0; r < 16; ++r) {
      int m = mb + (r & 3) + 8 * (r >> 2);
      int b = m >> log2n;
      int idx = m & (n - 1);
      float gi = sigmoid_f(acc[mt][0][r] + b0);
      float gl = sigmoid_f(acc[mt][1][r] + b1);
      float gr = sigmoid_f(acc[mt][2][r] + b2);
      float go = sigmoid_f(acc[mt][3][r] + b3);
      float gu = tanh_f(acc[mt][4][r] + b4);
      float cv = gi * gu;
      if (!leaf) {
        size_t cb = ((size_t)b * 2 * n + 2 * idx) * HDIM + j;
        cv += gl * c_prev[cb] + gr * c_prev[cb + HDIM];
      }
      size_t ob = ((size_t)b * n + idx) * HDIM + j;
      c_out[ob] = cv;
      h_out[ob] = (__bf16)(go * tanh_f(cv));
    }
  }
}

__global__ __launch_bounds__(256) void cls_kernel(
    const __bf16* __restrict__ hroot, const float* __restrict__ Wc,
    const float* __restrict__ bc, float* __restrict__ out)
{
  int t = blockIdx.x * blockDim.x + threadIdx.x;
  if (t >= BATCH * NCLS) return;
  int b = t / NCLS, ci = t % NCLS;
  float s = bc[ci];
#pragma unroll 4
  for (int jj = 0; jj < HDIM; ++jj)
    s += (float)hroot[b * HDIM + jj] * Wc[ci * HDIM + jj];
  out[t] = s;
}

extern "C" void kernel_launch(void* const* d_in, const int* in_sizes, int n_in,
                              void* d_out, int out_size, void* d_ws, size_t ws_size,
                              hipStream_t stream) {
  const float* x  = (const float*)d_in[0];
  const float* W[5]  = {(const float*)d_in[1], (const float*)d_in[3], (const float*)d_in[5],
                        (const float*)d_in[7], (const float*)d_in[9]};
  const float* bv[5] = {(const float*)d_in[2], (const float*)d_in[4], (const float*)d_in[6],
                        (const float*)d_in[8], (const float*)d_in[10]};
  const float* Wcls = (const float*)d_in[11];
  const float* bcls = (const float*)d_in[12];

  // ws layout (ping-pong; buf0 holds odd-sized levels d=9,7,..: up to n=512;
  // buf1 holds d=8,6,..: up to n=256):
  uint8_t* ws = (uint8_t*)d_ws;
  __bf16* hb[2] = {(__bf16*)ws, (__bf16*)(ws + 33554432)};          // 32MB + 16MB
  float*  cb[2] = {(float*)(ws + 50331648), (float*)(ws + 117440512)}; // 64MB + 32MB
  __bf16* PW = (__bf16*)(ws + 150994944);                            // 480KB

  pack_w<<<120, 256, 0, stream>>>(W[0], W[1], W[2], W[3], W[4], PW);

  for (int d = TDEPTH - 1; d >= 0; --d) {
    int n = 1 << d;
    int wi = (TDEPTH - 1 - d) & 1;
    int ri = wi ^ 1;
    int leaf = (d == TDEPTH - 1) ? 1 : 0;
    dim3 grid(2 * n, 2);  // (B*n/128) x (128/64 j-range)
    level_kernel<<<grid, 256, 0, stream>>>(
        x, PW, bv[0], bv[1], bv[2], bv[3], bv[4],
        hb[ri], cb[ri], hb[wi], cb[wi], n, d, leaf);
  }
  cls_kernel<<<(BATCH * NCLS + 255) / 256, 256, 0, stream>>>(hb[1], Wcls, bcls, (float*)d_out);
}